// Round 3
// baseline (104.267 us; speedup 1.0000x reference)
//
#include <hip/hip_runtime.h>

// KroneSoftmax: x[2, 2048, 256] fp32.
// out[b, a*256+k] = softmax_row( x[0][b,a] * x[1][b,k] )
// One block per row. Memory-bound: 512 MiB output writes dominate.
// Opt round 2: exp2-folding (1 fma + 1 v_exp per element), 4-acc denominator,
// nontemporal float4 stores (via native ext_vector type — HIP float4 is a
// class and rejected by __builtin_nontemporal_store).

constexpr int FA   = 256;
constexpr int FB   = 256;
constexpr int ROWS = 2048;

typedef float f32x4 __attribute__((ext_vector_type(4)));

__global__ __launch_bounds__(256) void krone_softmax_kernel(
    const float* __restrict__ x, float* __restrict__ out) {
  const int row = blockIdx.x;
  const int tid = threadIdx.x;

  const float* __restrict__ xa = x + (size_t)row * FA;
  const float* __restrict__ xb = x + (size_t)ROWS * FA + (size_t)row * FB;

  __shared__ float sa[FA];
  __shared__ float sb[FB];
  __shared__ float wred[4][4];   // per-wave {maxa, mina, maxb, minb}
  __shared__ float wsum[4];

  const float a = xa[tid];
  const float b = xb[tid];
  sa[tid] = a;
  sb[tid] = b;

  // ---- row max of bilinear form via vector extremes (exact) ----
  float maxa = a, mina = a, maxb = b, minb = b;
#pragma unroll
  for (int off = 32; off > 0; off >>= 1) {
    maxa = fmaxf(maxa, __shfl_xor(maxa, off));
    mina = fminf(mina, __shfl_xor(mina, off));
    maxb = fmaxf(maxb, __shfl_xor(maxb, off));
    minb = fminf(minb, __shfl_xor(minb, off));
  }
  const int wid = tid >> 6;
  if ((tid & 63) == 0) {
    wred[wid][0] = maxa; wred[wid][1] = mina;
    wred[wid][2] = maxb; wred[wid][3] = minb;
  }
  __syncthreads();
  const float MA = fmaxf(fmaxf(wred[0][0], wred[1][0]), fmaxf(wred[2][0], wred[3][0]));
  const float mA = fminf(fminf(wred[0][1], wred[1][1]), fminf(wred[2][1], wred[3][1]));
  const float MB = fmaxf(fmaxf(wred[0][2], wred[1][2]), fmaxf(wred[2][2], wred[3][2]));
  const float mB = fminf(fminf(wred[0][3], wred[1][3]), fminf(wred[2][3], wred[3][3]));
  const float M = fmaxf(fmaxf(MA * MB, MA * mB), fmaxf(mA * MB, mA * mB));

  constexpr float LOG2E = 1.4426950408889634f;
  const float mM2 = -M * LOG2E;

  // ---- denominator: thread owns column j = tid, loop over a rows ----
  // exp(a*b - M) = exp2(a * (b*log2e) + (-M*log2e)); 4 accumulators to
  // break the fp-add dependency chain.
  const float bs = b * LOG2E;
  float s0 = 0.f, s1 = 0.f, s2 = 0.f, s3 = 0.f;
#pragma unroll 4
  for (int i = 0; i < FA; i += 4) {
    s0 += __builtin_amdgcn_exp2f(fmaf(sa[i + 0], bs, mM2));
    s1 += __builtin_amdgcn_exp2f(fmaf(sa[i + 1], bs, mM2));
    s2 += __builtin_amdgcn_exp2f(fmaf(sa[i + 2], bs, mM2));
    s3 += __builtin_amdgcn_exp2f(fmaf(sa[i + 3], bs, mM2));
  }
  float s = (s0 + s1) + (s2 + s3);
#pragma unroll
  for (int off = 32; off > 0; off >>= 1) s += __shfl_xor(s, off);
  if ((tid & 63) == 0) wsum[wid] = s;
  __syncthreads();
  const float sum = (wsum[0] + wsum[1]) + (wsum[2] + wsum[3]);

  // out = exp(a*b - M)/sum = exp2( a*(b*log2e) + C ),
  // C = -M*log2e - log2(sum)
  const float C = mM2 - __builtin_amdgcn_logf(sum);

  // ---- output: 64 iters x 256 threads x float4, fully coalesced ----
  float* __restrict__ orow = out + (size_t)row * (FA * FB);
  const int ai_base = tid >> 6;            // wave-uniform a-row within quad
  const int j = (tid & 63) * 4;
  f32x4 b4 = *reinterpret_cast<const f32x4*>(&sb[j]);
  b4 *= LOG2E;
#pragma unroll 8
  for (int it = 0; it < 64; ++it) {
    const float av = sa[it * 4 + ai_base]; // wave-uniform broadcast
    f32x4 v;
    v.x = __builtin_amdgcn_exp2f(fmaf(av, b4.x, C));
    v.y = __builtin_amdgcn_exp2f(fmaf(av, b4.y, C));
    v.z = __builtin_amdgcn_exp2f(fmaf(av, b4.z, C));
    v.w = __builtin_amdgcn_exp2f(fmaf(av, b4.w, C));
    __builtin_nontemporal_store(v, reinterpret_cast<f32x4*>(&orow[it * 1024 + tid * 4]));
  }
}

extern "C" void kernel_launch(void* const* d_in, const int* in_sizes, int n_in,
                              void* d_out, int out_size, void* d_ws, size_t ws_size,
                              hipStream_t stream) {
  const float* x = (const float*)d_in[0];
  float* out = (float*)d_out;
  krone_softmax_kernel<<<ROWS, 256, 0, stream>>>(x, out);
}

// Round 4
// 103.963 us; speedup vs baseline: 1.0029x; 1.0029x over previous
//
#include <hip/hip_runtime.h>

// KroneSoftmax: x[2, 2048, 256] fp32.
// out[b, a*256+k] = softmax_row( x[0][b,a] * x[1][b,k] )
// One block per row. Memory-bound: 512 MiB output writes dominate.
// Round 3: per-wave CONTIGUOUS 64 KB write streams (wave w owns a-rows
// [w*64, w*64+64)), instead of 4-wave-interleaved 1KB chunks. Targets DRAM
// row locality / write-combining. Compute identical to round 2.

constexpr int FA   = 256;
constexpr int FB   = 256;
constexpr int ROWS = 2048;

typedef float f32x4 __attribute__((ext_vector_type(4)));

__global__ __launch_bounds__(256) void krone_softmax_kernel(
    const float* __restrict__ x, float* __restrict__ out) {
  const int row = blockIdx.x;
  const int tid = threadIdx.x;

  const float* __restrict__ xa = x + (size_t)row * FA;
  const float* __restrict__ xb = x + (size_t)ROWS * FA + (size_t)row * FB;

  __shared__ float sa[FA];
  __shared__ float sb[FB];
  __shared__ float wred[4][4];   // per-wave {maxa, mina, maxb, minb}
  __shared__ float wsum[4];

  const float a = xa[tid];
  const float b = xb[tid];
  sa[tid] = a;
  sb[tid] = b;

  // ---- row max of bilinear form via vector extremes (exact) ----
  float maxa = a, mina = a, maxb = b, minb = b;
#pragma unroll
  for (int off = 32; off > 0; off >>= 1) {
    maxa = fmaxf(maxa, __shfl_xor(maxa, off));
    mina = fminf(mina, __shfl_xor(mina, off));
    maxb = fmaxf(maxb, __shfl_xor(maxb, off));
    minb = fminf(minb, __shfl_xor(minb, off));
  }
  const int wid = tid >> 6;
  if ((tid & 63) == 0) {
    wred[wid][0] = maxa; wred[wid][1] = mina;
    wred[wid][2] = maxb; wred[wid][3] = minb;
  }
  __syncthreads();
  const float MA = fmaxf(fmaxf(wred[0][0], wred[1][0]), fmaxf(wred[2][0], wred[3][0]));
  const float mA = fminf(fminf(wred[0][1], wred[1][1]), fminf(wred[2][1], wred[3][1]));
  const float MB = fmaxf(fmaxf(wred[0][2], wred[1][2]), fmaxf(wred[2][2], wred[3][2]));
  const float mB = fminf(fminf(wred[0][3], wred[1][3]), fminf(wred[2][3], wred[3][3]));
  const float M = fmaxf(fmaxf(MA * MB, MA * mB), fmaxf(mA * MB, mA * mB));

  constexpr float LOG2E = 1.4426950408889634f;
  const float mM2 = -M * LOG2E;

  // ---- denominator: thread owns column j = tid, loop over a rows ----
  const float bs = b * LOG2E;
  float s0 = 0.f, s1 = 0.f, s2 = 0.f, s3 = 0.f;
#pragma unroll 4
  for (int i = 0; i < FA; i += 4) {
    s0 += __builtin_amdgcn_exp2f(fmaf(sa[i + 0], bs, mM2));
    s1 += __builtin_amdgcn_exp2f(fmaf(sa[i + 1], bs, mM2));
    s2 += __builtin_amdgcn_exp2f(fmaf(sa[i + 2], bs, mM2));
    s3 += __builtin_amdgcn_exp2f(fmaf(sa[i + 3], bs, mM2));
  }
  float s = (s0 + s1) + (s2 + s3);
#pragma unroll
  for (int off = 32; off > 0; off >>= 1) s += __shfl_xor(s, off);
  if ((tid & 63) == 0) wsum[wid] = s;
  __syncthreads();
  const float sum = (wsum[0] + wsum[1]) + (wsum[2] + wsum[3]);

  // out = exp2( a*(b*log2e) + C ),  C = -M*log2e - log2(sum)
  const float C = mM2 - __builtin_amdgcn_logf(sum);

  // ---- output: wave w owns a-rows [w*64, w*64+64) => contiguous 64 KB ----
  // Iteration it stores the full 1 KB b-row of a = w*64+it; per-wave address
  // stream is strictly sequential.
  float* __restrict__ orow = out + (size_t)row * (FA * FB);
  const int lane = tid & 63;
  const int j = lane * 4;
  f32x4 b4 = *reinterpret_cast<const f32x4*>(&sb[j]);
  b4 *= LOG2E;
  float* __restrict__ oseg = orow + wid * (64 * FB);  // 64 KB per wave
#pragma unroll 8
  for (int it = 0; it < 64; ++it) {
    const float av = sa[wid * 64 + it];  // wave-uniform broadcast
    f32x4 v;
    v.x = __builtin_amdgcn_exp2f(fmaf(av, b4.x, C));
    v.y = __builtin_amdgcn_exp2f(fmaf(av, b4.y, C));
    v.z = __builtin_amdgcn_exp2f(fmaf(av, b4.z, C));
    v.w = __builtin_amdgcn_exp2f(fmaf(av, b4.w, C));
    __builtin_nontemporal_store(v, reinterpret_cast<f32x4*>(&oseg[it * FB + j]));
  }
}

extern "C" void kernel_launch(void* const* d_in, const int* in_sizes, int n_in,
                              void* d_out, int out_size, void* d_ws, size_t ws_size,
                              hipStream_t stream) {
  const float* x = (const float*)d_in[0];
  float* out = (float*)d_out;
  krone_softmax_kernel<<<ROWS, 256, 0, stream>>>(x, out);
}